// Round 8
// baseline (19206.483 us; speedup 1.0000x reference)
//
#include <hip/hip_runtime.h>
#include <math.h>

// ---------------------------------------------------------------------------
// Seq2SeqLSTM on MI355X -- Round 7: R5 chain + vector-path weights +
// read-only per-WG flag slots + poll backoff.
//
// Evidence: R3/R4/R5 invariant ~17us/phase across sync designs; R6 removed
// all same-address RMWs but regressed via 4x-duplicated UNCACHED slab reads
// (WRITE_SIZE 8.5->66.8MB) -> RMW serialization refuted. Remaining suspects
// attacked here, protocol otherwise identical to R5 (known correct):
//  1) weight loads were scalar-path (wave-uniform pointers) -> K$ thrash
//     (48KB/WG vs 16KB K$ every phase). Fix: opaque-zero VGPR added to each
//     weight pointer forces vector-path loads (uniform addr = 1 L1 line
//     broadcast); 48KB/WG ~ L1-resident.
//  2) poll storms: busy-spin polls saturate flag lines. Fix: read-only poll
//     of per-WG monotonic slots fA[64]/fB[64] (R6 protocol) + s_sleep(1).
//  3) slab exchange stays LDS-staged (single pass per WG) -- R6 confound out.
// ---------------------------------------------------------------------------

#define B     64
#define SLEN  64
#define TLEN  32
#define HID   256
#define EMBD  256
#define G4    1024
#define VOC   32000
#define NPRED 31
#define NWG   64

typedef float v2f __attribute__((ext_vector_type(2)));
typedef unsigned long long u64;

__device__ __forceinline__ float sigf(float x){ return 1.0f/(1.0f+__expf(-x)); }

__device__ __forceinline__ void gstoref(float* p, float v){
  __hip_atomic_store(p, v, __ATOMIC_RELAXED, __HIP_MEMORY_SCOPE_AGENT);
}
__device__ __forceinline__ void gstorei(int* p, int v){
  __hip_atomic_store(p, v, __ATOMIC_RELAXED, __HIP_MEMORY_SCOPE_AGENT);
}
__device__ __forceinline__ u64 gload64(const u64* p){
  return __hip_atomic_load(p, __ATOMIC_RELAXED, __HIP_MEMORY_SCOPE_AGENT);
}
__device__ __forceinline__ int gload32(const int* p){
  return __hip_atomic_load(p, __ATOMIC_RELAXED, __HIP_MEMORY_SCOPE_AGENT);
}

// --------------------------------- init ------------------------------------
__global__ void k_init(const int* __restrict__ tgt, int* __restrict__ buf){
  int r = threadIdx.x;
  if (r < B) buf[r*TLEN] = tgt[r*TLEN];
}

__global__ void k_zero(int* __restrict__ p){
  p[threadIdx.x] = 0;
}

// --------------------------------- xproj -----------------------------------
// out[(pos*G4 + j)*64 + r] = b0[j] + sum_k emb[tok[r]][k] * W[j][k]
__global__ __launch_bounds__(256) void k_xproj(
    const int* __restrict__ tok, int tok_stride, int pos0,
    const float* __restrict__ emb, const float* __restrict__ W,
    const float* __restrict__ b0, float* __restrict__ out)
{
  __shared__ float xT[128][64];
  const int tid  = threadIdx.x;
  const int lane = tid & 63;
  const int wv   = __builtin_amdgcn_readfirstlane(tid >> 6);
  const int pos  = pos0 + blockIdx.y;
  const int jbase= blockIdx.x*32 + wv*8;

  const int rS = tid >> 2, klane = tid & 3;
  const int tokrow = tok[rS*tok_stride + pos];
  const float* xsrc = emb + (size_t)tokrow*EMBD;

  float acc[8];
  #pragma unroll
  for (int jj=0;jj<8;jj++) acc[jj]=0.f;

  for (int c=0;c<2;c++){
    __syncthreads();
    #pragma unroll
    for (int i=0;i<32;i++){
      int k = klane + 4*i;
      xT[k][rS] = xsrc[c*128 + k];
    }
    __syncthreads();
    for (int kc=0;kc<8;kc++){
      float x[16];
      #pragma unroll
      for (int i=0;i<16;i++) x[i] = xT[kc*16+i][lane];
      #pragma unroll
      for (int jj=0;jj<8;jj++){
        const float* Wp = W + (size_t)(jbase+jj)*EMBD + c*128 + kc*16;
        float s = 0.f;
        #pragma unroll
        for (int i=0;i<16;i++) s += Wp[i]*x[i];
        acc[jj] += s;
      }
    }
  }
  #pragma unroll
  for (int jj=0;jj<8;jj++){
    int j = jbase+jj;
    out[((size_t)pos*G4 + j)*64 + lane] = acc[jj] + b0[j];
  }
}

// --------------------------------- chain -----------------------------------
// Slabs h0T/h1T: [2 parities][16384 floats], paired layout: (jc,r) value at
// (jc>>1)*128 + 2r + (jc&1). h0P/h1P/c0P/c1P: plain [k][r] persistent state.
// fA[w]/fB[w]: monotonic publish counters per WG (cumulative via fbase).
__global__ __launch_bounds__(1024) void k_chain7(
    const float* __restrict__ xp, int nsteps,
    const float* __restrict__ Whh0, const float* __restrict__ Wih1,
    const float* __restrict__ Whh1, const float* __restrict__ b1,
    float* __restrict__ h0P, float* __restrict__ h1P,
    float* __restrict__ c0P, float* __restrict__ c1P,
    float* __restrict__ h0T, float* __restrict__ h1T,
    int* __restrict__ fA, int* __restrict__ fB, int fbase, int initzero)
{
  __shared__ __align__(16) float h0s[16384];     // 64 KB, paired layout
  __shared__ __align__(16) float h1s[16384];     // 64 KB, paired layout
  __shared__ float pL0[12][4][64];               // kq>=1 L0 partials
  __shared__ float pL1[12][4][64];               // kq!=1 L1 partials
  __shared__ int a0c, a1c;

  const int tid  = threadIdx.x;
  const int lane = tid & 63;
  const int wv   = __builtin_amdgcn_readfirstlane(tid >> 6);
  const int jsub = wv & 3, kq = wv >> 2;
  const int bid  = blockIdx.x;
  const int j    = bid*4 + jsub;        // h column in [0,256)
  const int k0   = kq << 6;             // k slice of 64

  // opaque zero in a VGPR: forces weight pointers onto the VECTOR load path
  // (uniform address -> single L1-line broadcast per load, no K$ involvement)
  int zr; asm("v_mov_b32 %0, 0" : "=v"(zr));

  const v2f* Wr0 = (const v2f*)(Whh0 + (size_t)(0*HID+j)*HID + k0) + zr;
  const v2f* Wr1 = (const v2f*)(Whh0 + (size_t)(1*HID+j)*HID + k0) + zr;
  const v2f* Wr2 = (const v2f*)(Whh0 + (size_t)(2*HID+j)*HID + k0) + zr;
  const v2f* Wr3 = (const v2f*)(Whh0 + (size_t)(3*HID+j)*HID + k0) + zr;
  const v2f* Wi0 = (const v2f*)(Wih1 + (size_t)(0*HID+j)*HID + k0) + zr;
  const v2f* Wi1 = (const v2f*)(Wih1 + (size_t)(1*HID+j)*HID + k0) + zr;
  const v2f* Wi2 = (const v2f*)(Wih1 + (size_t)(2*HID+j)*HID + k0) + zr;
  const v2f* Wi3 = (const v2f*)(Wih1 + (size_t)(3*HID+j)*HID + k0) + zr;
  const v2f* Wh0 = (const v2f*)(Whh1 + (size_t)(0*HID+j)*HID + k0) + zr;
  const v2f* Wh1 = (const v2f*)(Whh1 + (size_t)(1*HID+j)*HID + k0) + zr;
  const v2f* Wh2 = (const v2f*)(Whh1 + (size_t)(2*HID+j)*HID + k0) + zr;
  const v2f* Wh3 = (const v2f*)(Whh1 + (size_t)(3*HID+j)*HID + k0) + zr;

  float c0 = 0.f, c1 = 0.f;
  float bb0=0.f, bb1=0.f, bb2=0.f, bb3=0.f;
  if (wv < 4 && !initzero)              c0 = c0P[j*64 + lane];
  if (wv >= 4 && wv < 8){
    bb0 = b1[0*HID+j]; bb1 = b1[1*HID+j];
    bb2 = b1[2*HID+j]; bb3 = b1[3*HID+j];
    if (!initzero)                      c1 = c1P[j*64 + lane];
  }
  if (tid == 0){ a0c = 0; a1c = 0; }

  for (int q = 0; q <= nsteps; ++q){
    // ---- A: wave 0 polls per-WG monotonic slots (read-only, backoff)
    if (wv == 0 && q >= 1){
      const int tA = fbase + q, tB = fbase + q - 1;
      int g = 0;
      for(;;){
        int va = gload32(fA + lane);
        int ok = (va >= tA);
        if (q >= 2){ int vb = gload32(fB + lane); ok &= (vb >= tB); }
        if (__all(ok) || ++g > (1<<24)) break;
        __builtin_amdgcn_s_sleep(1);
      }
    }
    __syncthreads();   // A
    asm volatile("" ::: "memory");

    // act0 xp prefetch (consumed after C0)
    float xv0=0.f, xv1=0.f, xv2=0.f, xv3=0.f;
    if (wv < 4 && q < nsteps){
      const float* xq = xp + ((size_t)q*G4)*64 + lane;
      xv0 = xq[(0*HID+j)*64]; xv1 = xq[(1*HID+j)*64];
      xv2 = xq[(2*HID+j)*64]; xv3 = xq[(3*HID+j)*64];
    }

    // ---- stage h0s <- h0(q-1), h1s <- h1(q-2)
    if (q == 0){
      if (initzero){
        u64* d = (u64*)h0s;
        #pragma unroll
        for (int i=0;i<8;i++) d[tid + i*1024] = 0ull;
      } else {
        #pragma unroll
        for (int i=0;i<8;i++){
          int p = tid + i*1024, kp = p >> 6, r = p & 63;
          v2f v; v.x = h0P[(2*kp)*64 + r]; v.y = h0P[(2*kp+1)*64 + r];
          ((v2f*)h0s)[p] = v;
        }
      }
    } else {
      const u64* s = (const u64*)(h0T + (size_t)((q-1)&1)*16384);
      u64* d = (u64*)h0s;
      #pragma unroll
      for (int i=0;i<8;i++) d[tid + i*1024] = gload64(s + tid + i*1024);
    }
    if (q <= 1){
      if (initzero){
        u64* d = (u64*)h1s;
        #pragma unroll
        for (int i=0;i<8;i++) d[tid + i*1024] = 0ull;
      } else {
        #pragma unroll
        for (int i=0;i<8;i++){
          int p = tid + i*1024, kp = p >> 6, r = p & 63;
          v2f v; v.x = h1P[(2*kp)*64 + r]; v.y = h1P[(2*kp+1)*64 + r];
          ((v2f*)h1s)[p] = v;
        }
      }
    } else {
      const u64* s = (const u64*)(h1T + (size_t)(q&1)*16384);
      u64* d = (u64*)h1s;
      #pragma unroll
      for (int i=0;i<8;i++) d[tid + i*1024] = gload64(s + tid + i*1024);
    }
    __syncthreads();   // B

    // ---- L0 partials for step q (vector weight loads, float2 pk-fma)
    v2f A0={0.f,0.f}, A1={0.f,0.f}, A2={0.f,0.f}, A3={0.f,0.f};
    if (q < nsteps){
      const v2f* hp = ((const v2f*)h0s) + kq*2048 + lane;
      #pragma unroll 4
      for (int kk=0; kk<32; ++kk){
        v2f h = hp[kk*64];
        A0 += Wr0[kk]*h; A1 += Wr1[kk]*h; A2 += Wr2[kk]*h; A3 += Wr3[kk]*h;
      }
      if (kq >= 1){
        int s = (kq-1)*4 + jsub;
        pL0[s][0][lane]=A0.x+A0.y; pL0[s][1][lane]=A1.x+A1.y;
        pL0[s][2][lane]=A2.x+A2.y; pL0[s][3][lane]=A3.x+A3.y;
      }
    }
    __syncthreads();   // C0

    // ---- act0 (waves 0-3): reduce + activate + publish h0(q)
    if (wv < 4 && q < nsteps){
      __builtin_amdgcn_s_setprio(1);
      float g0 = A0.x+A0.y + xv0, g1 = A1.x+A1.y + xv1;
      float g2 = A2.x+A2.y + xv2, g3 = A3.x+A3.y + xv3;
      #pragma unroll
      for (int i=0;i<3;i++){
        g0 += pL0[i*4+jsub][0][lane]; g1 += pL0[i*4+jsub][1][lane];
        g2 += pL0[i*4+jsub][2][lane]; g3 += pL0[i*4+jsub][3][lane];
      }
      c0 = sigf(g1)*c0 + sigf(g0)*tanhf(g2);
      float h = sigf(g3)*tanhf(c0);
      gstoref(h0T + (size_t)(q&1)*16384 + (j>>1)*128 + 2*lane + (j&1), h);
      if (q == nsteps-1) h0P[j*64 + lane] = h;
      asm volatile("s_waitcnt vmcnt(0)" ::: "memory");
      if (lane == 0){
        int old = atomicAdd(&a0c, 1);
        if (old == 3){ a0c = 0; gstorei(fA + bid, fbase + q + 1); }
      }
      __builtin_amdgcn_s_setprio(0);
    }

    // ---- L1 partials for step q-1 (h0s = h0(q-1), h1s = h1(q-2))
    v2f B0={0.f,0.f}, B1={0.f,0.f}, B2={0.f,0.f}, B3={0.f,0.f};
    if (q >= 1){
      const v2f* ha = ((const v2f*)h0s) + kq*2048 + lane;
      const v2f* hb = ((const v2f*)h1s) + kq*2048 + lane;
      #pragma unroll 2
      for (int kk=0; kk<32; ++kk){
        v2f x = ha[kk*64], y = hb[kk*64];
        B0 += Wi0[kk]*x + Wh0[kk]*y;
        B1 += Wi1[kk]*x + Wh1[kk]*y;
        B2 += Wi2[kk]*x + Wh2[kk]*y;
        B3 += Wi3[kk]*x + Wh3[kk]*y;
      }
      if (kq != 1){
        int s = ((kq==0) ? 0 : (kq-1))*4 + jsub;
        pL1[s][0][lane]=B0.x+B0.y; pL1[s][1][lane]=B1.x+B1.y;
        pL1[s][2][lane]=B2.x+B2.y; pL1[s][3][lane]=B3.x+B3.y;
      }
    }
    __syncthreads();   // C1

    // ---- act1 (waves 4-7): reduce + activate + publish h1(q-1)
    if (wv >= 4 && wv < 8 && q >= 1){
      float g0 = B0.x+B0.y + bb0, g1 = B1.x+B1.y + bb1;
      float g2 = B2.x+B2.y + bb2, g3 = B3.x+B3.y + bb3;
      #pragma unroll
      for (int i=0;i<3;i++){
        g0 += pL1[i*4+jsub][0][lane]; g1 += pL1[i*4+jsub][1][lane];
        g2 += pL1[i*4+jsub][2][lane]; g3 += pL1[i*4+jsub][3][lane];
      }
      c1 = sigf(g1)*c1 + sigf(g0)*tanhf(g2);
      float h = sigf(g3)*tanhf(c1);
      gstoref(h1T + (size_t)((q-1)&1)*16384 + (j>>1)*128 + 2*lane + (j&1), h);
      if (q == nsteps) h1P[j*64 + lane] = h;
      asm volatile("s_waitcnt vmcnt(0)" ::: "memory");
      if (lane == 0){
        int old = atomicAdd(&a1c, 1);
        if (old == 3){ a1c = 0; gstorei(fB + bid, fbase + q); }
      }
    }
  }

  if (wv < 4)               c0P[j*64 + lane] = c0;
  if (wv >= 4 && wv < 8)    c1P[j*64 + lane] = c1;
}

// --------------------------------- pred ------------------------------------
__global__ __launch_bounds__(256) void k_pred(
    const float* __restrict__ h1, const float* __restrict__ Wout,
    const float* __restrict__ bout, float* __restrict__ dout, int t,
    float* __restrict__ pval, int* __restrict__ pidx)
{
  __shared__ float xT[128][64];
  __shared__ float cval[4][64];
  __shared__ int   cidx[4][64];
  const int tid  = threadIdx.x;
  const int lane = tid & 63;
  const int wv   = __builtin_amdgcn_readfirstlane(tid >> 6);
  const int vbase= blockIdx.x*32 + wv*8;

  float acc[8];
  #pragma unroll
  for (int vv=0;vv<8;vv++) acc[vv]=0.f;

  for (int c=0;c<2;c++){
    __syncthreads();
    {
      const float4* s4 = (const float4*)(h1 + c*8192);
      float4* d4 = (float4*)&xT[0][0];
      #pragma unroll
      for (int i=0;i<8;i++) d4[tid + i*256] = s4[tid + i*256];
    }
    __syncthreads();
    for (int kc=0;kc<8;kc++){
      float x[16];
      #pragma unroll
      for (int i=0;i<16;i++) x[i] = xT[kc*16+i][lane];
      #pragma unroll
      for (int vv=0;vv<8;vv++){
        const float* Wp = Wout + (size_t)(vbase+vv)*HID + c*128 + kc*16;
        float s = 0.f;
        #pragma unroll
        for (int i=0;i<16;i++) s += Wp[i]*x[i];
        acc[vv] += s;
      }
    }
  }

  const int r = lane;
  float best = -INFINITY; int bi = 0;
  #pragma unroll
  for (int vv=0; vv<8; vv++){
    int v = vbase + vv;
    float val = acc[vv] + bout[v];
    dout[((size_t)r*NPRED + t)*VOC + v] = val;
    if (val > best){ best = val; bi = v; }
  }
  cval[wv][lane] = best; cidx[wv][lane] = bi;
  __syncthreads();
  if (tid < 64){
    float bb = cval[0][tid]; int bbi = cidx[0][tid];
    #pragma unroll
    for (int w=1; w<4; w++){
      float v = cval[w][tid];
      if (v > bb){ bb = v; bbi = cidx[w][tid]; }
    }
    pval[(size_t)tid*1024 + blockIdx.x] = bb;
    pidx[(size_t)tid*1024 + blockIdx.x] = bbi;
  }
}

// ------------------------------ argmax final --------------------------------
__global__ __launch_bounds__(256) void k_amax(
    const float* __restrict__ pval, const int* __restrict__ pidx,
    int* __restrict__ buf, int t)
{
  __shared__ float sv[256]; __shared__ int si[256];
  const int r = blockIdx.x, tid = threadIdx.x;
  float best = -INFINITY; int bi = 0x7fffffff;
  for (int w = tid; w < 1000; w += 256){
    float v = pval[(size_t)r*1024 + w]; int ii = pidx[(size_t)r*1024 + w];
    if (v > best || (v == best && ii < bi)){ best = v; bi = ii; }
  }
  sv[tid] = best; si[tid] = bi;
  __syncthreads();
  for (int s2 = 128; s2 > 0; s2 >>= 1){
    if (tid < s2){
      float v = sv[tid+s2]; int ii = si[tid+s2];
      if (v > sv[tid] || (v == sv[tid] && ii < si[tid])){ sv[tid]=v; si[tid]=ii; }
    }
    __syncthreads();
  }
  if (tid == 0) buf[r*TLEN + t + 1] = si[0];
}

// -------------------------------- launch ------------------------------------
extern "C" void kernel_launch(void* const* d_in, const int* in_sizes, int n_in,
                              void* d_out, int out_size, void* d_ws, size_t ws_size,
                              hipStream_t stream)
{
  const int*   input_seq  = (const int*)d_in[0];
  const int*   target_seq = (const int*)d_in[1];
  const float* enc_emb = (const float*)d_in[2];
  const float* dec_emb = (const float*)d_in[3];
  const float* enc_Wih = (const float*)d_in[4];
  const float* enc_Whh = (const float*)d_in[5];
  const float* enc_b   = (const float*)d_in[6];
  const float* dec_Wih = (const float*)d_in[7];
  const float* dec_Whh = (const float*)d_in[8];
  const float* dec_b   = (const float*)d_in[9];
  const float* W_out   = (const float*)d_in[10];
  const float* b_out   = (const float*)d_in[11];
  float* out = (float*)d_out;

  float* ws   = (float*)d_ws;
  float* xp_e = ws;                               // 64*1024*64
  float* xp_d = xp_e + (size_t)SLEN*G4*64;        // 32*1024*64
  float* h0P  = xp_d + (size_t)TLEN*G4*64;        // 256*64
  float* h1P  = h0P + HID*64;
  float* c0P  = h1P + HID*64;
  float* c1P  = c0P + HID*64;
  float* h0T  = c1P + HID*64;                     // 2*16384 (paired slabs)
  float* h1T  = h0T + 2*HID*64;
  float* pval = h1T + 2*HID*64;                   // 64*1024
  int*   pidx = (int*)(pval + (size_t)B*1024);    // 64*1024
  int*   buf  = pidx + (size_t)B*1024;            // 64*32
  int*   fA   = buf + B*TLEN;                     // 64
  int*   fB   = fA + 64;                          // 64

  k_init<<<1, 64, 0, stream>>>(target_seq, buf);
  k_zero<<<1, 128, 0, stream>>>(fA);              // zeroes fA+fB

  // encoder
  k_xproj<<<dim3(32, SLEN), 256, 0, stream>>>(input_seq, SLEN, 0, enc_emb,
        enc_Wih, enc_b, xp_e);
  k_chain7<<<NWG, 1024, 0, stream>>>(xp_e, SLEN,
        enc_Whh, enc_Wih + (size_t)G4*EMBD, enc_Whh + (size_t)G4*HID,
        enc_b + G4, h0P, h1P, c0P, c1P, h0T, h1T, fA, fB, 0, 1);

  // decoder greedy loop (outer step t replays positions 0..t)
  int fb = SLEN;
  for (int t = 0; t < NPRED; t++){
    k_xproj<<<dim3(32, 1), 256, 0, stream>>>(buf, TLEN, t, dec_emb,
        dec_Wih, dec_b, xp_d);
    k_chain7<<<NWG, 1024, 0, stream>>>(xp_d, t+1,
        dec_Whh, dec_Wih + (size_t)G4*EMBD, dec_Whh + (size_t)G4*HID,
        dec_b + G4, h0P, h1P, c0P, c1P, h0T, h1T, fA, fB, fb, 0);
    fb += t + 1;
    k_pred<<<1000, 256, 0, stream>>>(h1P, W_out, b_out, out, t, pval, pidx);
    k_amax<<<B, 256, 0, stream>>>(pval, pidx, buf, t);
  }
}

// Round 9
// 8604.182 us; speedup vs baseline: 2.2322x; 2.2322x over previous
//
#include <hip/hip_runtime.h>
#include <math.h>

// ---------------------------------------------------------------------------
// Seq2SeqLSTM on MI355X -- Round 8: 3-stage per-row pipeline, zero cross-WG
// dependencies on the recurrence critical path.
//
// Evidence R3-R7: ANY cross-WG exchange on the step critical path costs
// ~16-17us regardless of sync mechanism (fenced barrier / relaxed flags /
// per-WG slots / vector vs scalar weights). Restructure instead:
//   A(r)  [WG 0..63]   : layer0 for row r. Streams Whh0^T only (1MB/step,
//                        R2-proven coalesced dotpart ~7.6us/MB). h0,c0 chain
//                        stays INSIDE the WG -> no sync on critical path.
//   B1(r) [WG 64..127] : Wih1^T . h0(q) partial (1MB/step), lags A by 1 step.
//   B2(r) [WG 128..191]: Whh1^T . h1 (1MB/step) + combine + act; h1,c1 local.
// Handoffs: depth-4 rings (h0R 1KB/step/row, p1R 4KB/step/row) with sc1
// stores + vmcnt + per-row monotonic flags (protocol proven R5-R7). Slack =
// one full stage (~8us), so exchange latency only adds pipeline fill.
// 192 WGs, LDS-forced 1 WG/CU -> co-residency guaranteed.
// ---------------------------------------------------------------------------

#define B     64
#define SLEN  64
#define TLEN  32
#define HID   256
#define EMBD  256
#define G4    1024
#define VOC   32000
#define NPRED 31

typedef unsigned long long u64;

__device__ __forceinline__ float sigf(float x){ return 1.0f/(1.0f+__expf(-x)); }

__device__ __forceinline__ void gstoref(float* p, float v){
  __hip_atomic_store(p, v, __ATOMIC_RELAXED, __HIP_MEMORY_SCOPE_AGENT);
}
__device__ __forceinline__ void gstorei(int* p, int v){
  __hip_atomic_store(p, v, __ATOMIC_RELAXED, __HIP_MEMORY_SCOPE_AGENT);
}
__device__ __forceinline__ float gloadf(const float* p){
  return __hip_atomic_load(p, __ATOMIC_RELAXED, __HIP_MEMORY_SCOPE_AGENT);
}
__device__ __forceinline__ int gload32(const int* p){
  return __hip_atomic_load(p, __ATOMIC_RELAXED, __HIP_MEMORY_SCOPE_AGENT);
}

// --------------------------------- init ------------------------------------
__global__ void k_init(const int* __restrict__ tgt, int* __restrict__ buf){
  int r = threadIdx.x;
  if (r < B) buf[r*TLEN] = tgt[r*TLEN];
}

__global__ void k_zero(int* __restrict__ p){
  if (threadIdx.x < 192) p[threadIdx.x] = 0;
}

// ------------------------------- transpose ----------------------------------
// src [1024][256] -> dst [256][1024] (WT[k][j]); 64x64 LDS tiles.
__global__ __launch_bounds__(256) void k_tr(const float* __restrict__ src,
                                            float* __restrict__ dst){
  __shared__ float t[64][65];
  const int r0 = blockIdx.x*64, c0 = blockIdx.y*64;
  const int lr = threadIdx.x>>6, lc = threadIdx.x&63;
  #pragma unroll
  for (int i=0;i<16;i++){
    int r = lr + i*4;
    t[r][lc] = src[(size_t)(r0+r)*256 + c0+lc];
  }
  __syncthreads();
  #pragma unroll
  for (int i=0;i<16;i++){
    int c = lr + i*4;
    dst[(size_t)(c0+c)*1024 + r0+lc] = t[lc][c];
  }
}

// --------------------------------- xproj -----------------------------------
// out[(pos*G4 + j)*64 + r] = b0[j] + sum_k emb[tok[r]][k] * W[j][k]
__global__ __launch_bounds__(256) void k_xproj(
    const int* __restrict__ tok, int tok_stride, int pos0,
    const float* __restrict__ emb, const float* __restrict__ W,
    const float* __restrict__ b0, float* __restrict__ out)
{
  __shared__ float xT[128][64];
  const int tid  = threadIdx.x;
  const int lane = tid & 63;
  const int wv   = __builtin_amdgcn_readfirstlane(tid >> 6);
  const int pos  = pos0 + blockIdx.y;
  const int jbase= blockIdx.x*32 + wv*8;

  const int rS = tid >> 2, klane = tid & 3;
  const int tokrow = tok[rS*tok_stride + pos];
  const float* xsrc = emb + (size_t)tokrow*EMBD;

  float acc[8];
  #pragma unroll
  for (int jj=0;jj<8;jj++) acc[jj]=0.f;

  for (int c=0;c<2;c++){
    __syncthreads();
    #pragma unroll
    for (int i=0;i<32;i++){
      int k = klane + 4*i;
      xT[k][rS] = xsrc[c*128 + k];
    }
    __syncthreads();
    for (int kc=0;kc<8;kc++){
      float x[16];
      #pragma unroll
      for (int i=0;i<16;i++) x[i] = xT[kc*16+i][lane];
      #pragma unroll
      for (int jj=0;jj<8;jj++){
        const float* Wp = W + (size_t)(jbase+jj)*EMBD + c*128 + kc*16;
        float s = 0.f;
        #pragma unroll
        for (int i=0;i<16;i++) s += Wp[i]*x[i];
        acc[jj] += s;
      }
    }
  }
  #pragma unroll
  for (int jj=0;jj<8;jj++){
    int j = jbase+jj;
    out[((size_t)pos*G4 + j)*64 + lane] = acc[jj] + b0[j];
  }
}

// ------------------------------- dotpart ------------------------------------
// WT layout [k][j] as float4 over j. Thread (kq,jg): k in [kq*64,kq*64+64),
// gates 4jg..4jg+3. Coalesced float4 weight loads; h broadcast from LDS.
__device__ __forceinline__ float4 dotpart(const float4* __restrict__ Wq,
                                          const float* __restrict__ hs,
                                          int kq, int jg){
  float ax=0.f, ay=0.f, az=0.f, aw=0.f;
  const float4* __restrict__ hq = (const float4*)(hs + (kq<<6));
  const float4* __restrict__ w  = Wq + (size_t)(kq<<6)*256 + jg;
  #pragma unroll 4
  for (int kk=0; kk<16; ++kk){
    float4 h4 = hq[kk];
    float4 w0 = w[0];
    float4 w1 = w[256];
    float4 w2 = w[512];
    float4 w3 = w[768];
    ax += w0.x*h4.x; ay += w0.y*h4.x; az += w0.z*h4.x; aw += w0.w*h4.x;
    ax += w1.x*h4.y; ay += w1.y*h4.y; az += w1.z*h4.y; aw += w1.w*h4.y;
    ax += w2.x*h4.z; ay += w2.y*h4.z; az += w2.z*h4.z; aw += w2.w*h4.z;
    ax += w3.x*h4.w; ay += w3.y*h4.w; az += w3.z*h4.w; aw += w3.w*h4.w;
    w += 1024;
  }
  return make_float4(ax,ay,az,aw);
}

// --------------------------------- pipe ------------------------------------
// h0R: [4][64][256] ring (A -> B1). p1R: [4][64][1024] ring (B1 -> B2).
// fA/fB1/fB2: per-row monotonic step counters (cumulative via fbase).
// h0P/h1P/c0P/c1P: [j][r] persistent state (plain ld/st; kernel-boundary
// coherence). LDS padded >80KB to force 1 WG/CU.
__global__ __launch_bounds__(1024) void k_pipe(
    const float* __restrict__ xp, int nsteps,
    const float* __restrict__ WT0, const float* __restrict__ WT1i,
    const float* __restrict__ WT1h, const float* __restrict__ b1,
    float* __restrict__ h0P, float* __restrict__ h1P,
    float* __restrict__ c0P, float* __restrict__ c1P,
    float* __restrict__ h0R, float* __restrict__ p1R,
    int* __restrict__ fA, int* __restrict__ fB1, int* __restrict__ fB2,
    int fbase, int initzero)
{
  __shared__ __align__(16) float part[4][4096];   // 64 KB
  __shared__ float xps[1024];                     // 4 KB
  __shared__ __align__(16) float hloc[256];       // 1 KB
  __shared__ float padL[4096];                    // 16 KB (occupancy clamp)
  const int tid  = threadIdx.x;
  const int kq   = tid >> 8, jg = tid & 255;
  const int role = blockIdx.x >> 6;
  const int r    = blockIdx.x & 63;
  if (nsteps < 0){ padL[tid] = xp[tid]; h0R[tid] = padL[tid ^ 1]; }

  if (role == 0){
    // ================= A: layer-0 recurrence (fully WG-local) ==============
    float c0 = 0.f;
    if (tid < HID){
      if (initzero){ c0 = 0.f; hloc[tid] = 0.f; }
      else { c0 = c0P[tid*64 + r]; hloc[tid] = h0P[tid*64 + r]; }
    }
    __syncthreads();
    const float4* W4 = (const float4*)WT0;
    for (int q = 0; q < nsteps; ++q){
      float xv = xp[((size_t)q*G4 + tid)*64 + r];      // 1 scalar/thread
      if (tid == 0 && q >= 4){                          // ring backpressure
        int tgt = fbase + q - 3, g = 0;
        while (gload32(fB1 + r) < tgt && ++g < (1<<24)) {}
      }
      xps[tid] = xv;
      float4 a = dotpart(W4, hloc, kq, jg);
      *(float4*)&part[kq][jg<<2] = a;
      __syncthreads();
      if (tid < HID){
        float g0 = part[0][tid]+part[1][tid]+part[2][tid]+part[3][tid] + xps[tid];
        float g1 = part[0][HID+tid]+part[1][HID+tid]+part[2][HID+tid]+part[3][HID+tid] + xps[HID+tid];
        float g2 = part[0][2*HID+tid]+part[1][2*HID+tid]+part[2][2*HID+tid]+part[3][2*HID+tid] + xps[2*HID+tid];
        float g3 = part[0][3*HID+tid]+part[1][3*HID+tid]+part[2][3*HID+tid]+part[3][3*HID+tid] + xps[3*HID+tid];
        c0 = sigf(g1)*c0 + sigf(g0)*tanhf(g2);
        float h = sigf(g3)*tanhf(c0);
        hloc[tid] = h;                                  // reads done pre-barrier
        gstoref(h0R + (q&3)*16384 + r*256 + tid, h);
        asm volatile("s_waitcnt vmcnt(0)" ::: "memory");
      }
      __syncthreads();
      if (tid == 0) gstorei(fA + r, fbase + q + 1);
    }
    if (tid < HID){ c0P[tid*64 + r] = c0; h0P[tid*64 + r] = hloc[tid]; }
  }
  else if (role == 1){
    // ================= B1: Wih1^T . h0(q) partial ==========================
    const float4* W4 = (const float4*)WT1i;
    for (int q = 0; q < nsteps; ++q){
      if (tid == 0){
        int tgt = fbase + q + 1, g = 0;
        while (gload32(fA + r) < tgt && ++g < (1<<24)) {}
        if (q >= 4){
          int t2 = fbase + q - 3; g = 0;
          while (gload32(fB2 + r) < t2 && ++g < (1<<24)) {}
        }
      }
      __syncthreads();
      if (tid < HID) hloc[tid] = gloadf(h0R + (q&3)*16384 + r*256 + tid);
      __syncthreads();                                  // drains loads
      float4 a = dotpart(W4, hloc, kq, jg);
      *(float4*)&part[kq][jg<<2] = a;
      __syncthreads();
      float p = part[0][tid]+part[1][tid]+part[2][tid]+part[3][tid];
      gstoref(p1R + (q&3)*65536 + r*1024 + tid, p);
      asm volatile("s_waitcnt vmcnt(0)" ::: "memory");
      __syncthreads();
      if (tid == 0) gstorei(fB1 + r, fbase + q + 1);
    }
  }
  else {
    // ================= B2: Whh1^T recurrence + combine + act ===============
    float c1 = 0.f, bb0=0.f, bb1=0.f, bb2=0.f, bb3=0.f;
    if (tid < HID){
      bb0 = b1[tid]; bb1 = b1[HID+tid]; bb2 = b1[2*HID+tid]; bb3 = b1[3*HID+tid];
      if (initzero){ c1 = 0.f; hloc[tid] = 0.f; }
      else { c1 = c1P[tid*64 + r]; hloc[tid] = h1P[tid*64 + r]; }
    }
    __syncthreads();
    const float4* W4 = (const float4*)WT1h;
    for (int q = 0; q < nsteps; ++q){
      if (tid == 0){
        int tgt = fbase + q + 1, g = 0;
        while (gload32(fB1 + r) < tgt && ++g < (1<<24)) {}
      }
      __syncthreads();
      xps[tid] = gloadf(p1R + (q&3)*65536 + r*1024 + tid);
      asm volatile("s_waitcnt vmcnt(0)" ::: "memory");
      __syncthreads();
      if (tid == 0) gstorei(fB2 + r, fbase + q + 1);    // slot consumed
      float4 a = dotpart(W4, hloc, kq, jg);
      *(float4*)&part[kq][jg<<2] = a;
      __syncthreads();
      if (tid < HID){
        float g0 = part[0][tid]+part[1][tid]+part[2][tid]+part[3][tid] + xps[tid] + bb0;
        float g1 = part[0][HID+tid]+part[1][HID+tid]+part[2][HID+tid]+part[3][HID+tid] + xps[HID+tid] + bb1;
        float g2 = part[0][2*HID+tid]+part[1][2*HID+tid]+part[2][2*HID+tid]+part[3][2*HID+tid] + xps[2*HID+tid] + bb2;
        float g3 = part[0][3*HID+tid]+part[1][3*HID+tid]+part[2][3*HID+tid]+part[3][3*HID+tid] + xps[3*HID+tid] + bb3;
        c1 = sigf(g1)*c1 + sigf(g0)*tanhf(g2);
        float h = sigf(g3)*tanhf(c1);
        hloc[tid] = h;
        if (q == nsteps-1) h1P[tid*64 + r] = h;         // for pred (kernel bdry)
      }
      __syncthreads();
    }
    if (tid < HID) c1P[tid*64 + r] = c1;
  }
}

// --------------------------------- pred ------------------------------------
// h1P layout [k][r] ([256][64]) -- flat coalesced staging (unchanged).
__global__ __launch_bounds__(256) void k_pred(
    const float* __restrict__ h1, const float* __restrict__ Wout,
    const float* __restrict__ bout, float* __restrict__ dout, int t,
    float* __restrict__ pval, int* __restrict__ pidx)
{
  __shared__ float xT[128][64];
  __shared__ float cval[4][64];
  __shared__ int   cidx[4][64];
  const int tid  = threadIdx.x;
  const int lane = tid & 63;
  const int wv   = __builtin_amdgcn_readfirstlane(tid >> 6);
  const int vbase= blockIdx.x*32 + wv*8;

  float acc[8];
  #pragma unroll
  for (int vv=0;vv<8;vv++) acc[vv]=0.f;

  for (int c=0;c<2;c++){
    __syncthreads();
    {
      const float4* s4 = (const float4*)(h1 + c*8192);
      float4* d4 = (float4*)&xT[0][0];
      #pragma unroll
      for (int i=0;i<8;i++) d4[tid + i*256] = s4[tid + i*256];
    }
    __syncthreads();
    for (int kc=0;kc<8;kc++){
      float x[16];
      #pragma unroll
      for (int i=0;i<16;i++) x[i] = xT[kc*16+i][lane];
      #pragma unroll
      for (int vv=0;vv<8;vv++){
        const float* Wp = Wout + (size_t)(vbase+vv)*HID + c*128 + kc*16;
        float s = 0.f;
        #pragma unroll
        for (int i=0;i<16;i++) s += Wp[i]*x[i];
        acc[vv] += s;
      }
    }
  }

  const int r = lane;
  float best = -INFINITY; int bi = 0;
  #pragma unroll
  for (int vv=0; vv<8; vv++){
    int v = vbase + vv;
    float val = acc[vv] + bout[v];
    dout[((size_t)r*NPRED + t)*VOC + v] = val;
    if (val > best){ best = val; bi = v; }
  }
  cval[wv][lane] = best; cidx[wv][lane] = bi;
  __syncthreads();
  if (tid < 64){
    float bb = cval[0][tid]; int bbi = cidx[0][tid];
    #pragma unroll
    for (int w=1; w<4; w++){
      float v = cval[w][tid];
      if (v > bb){ bb = v; bbi = cidx[w][tid]; }
    }
    pval[(size_t)tid*1024 + blockIdx.x] = bb;
    pidx[(size_t)tid*1024 + blockIdx.x] = bbi;
  }
}

// ------------------------------ argmax final --------------------------------
__global__ __launch_bounds__(256) void k_amax(
    const float* __restrict__ pval, const int* __restrict__ pidx,
    int* __restrict__ buf, int t)
{
  __shared__ float sv[256]; __shared__ int si[256];
  const int r = blockIdx.x, tid = threadIdx.x;
  float best = -INFINITY; int bi = 0x7fffffff;
  for (int w = tid; w < 1000; w += 256){
    float v = pval[(size_t)r*1024 + w]; int ii = pidx[(size_t)r*1024 + w];
    if (v > best || (v == best && ii < bi)){ best = v; bi = ii; }
  }
  sv[tid] = best; si[tid] = bi;
  __syncthreads();
  for (int s2 = 128; s2 > 0; s2 >>= 1){
    if (tid < s2){
      float v = sv[tid+s2]; int ii = si[tid+s2];
      if (v > sv[tid] || (v == sv[tid] && ii < si[tid])){ sv[tid]=v; si[tid]=ii; }
    }
    __syncthreads();
  }
  if (tid == 0) buf[r*TLEN + t + 1] = si[0];
}

// -------------------------------- launch ------------------------------------
extern "C" void kernel_launch(void* const* d_in, const int* in_sizes, int n_in,
                              void* d_out, int out_size, void* d_ws, size_t ws_size,
                              hipStream_t stream)
{
  const int*   input_seq  = (const int*)d_in[0];
  const int*   target_seq = (const int*)d_in[1];
  const float* enc_emb = (const float*)d_in[2];
  const float* dec_emb = (const float*)d_in[3];
  const float* enc_Wih = (const float*)d_in[4];
  const float* enc_Whh = (const float*)d_in[5];
  const float* enc_b   = (const float*)d_in[6];
  const float* dec_Wih = (const float*)d_in[7];
  const float* dec_Whh = (const float*)d_in[8];
  const float* dec_b   = (const float*)d_in[9];
  const float* W_out   = (const float*)d_in[10];
  const float* b_out   = (const float*)d_in[11];
  float* out = (float*)d_out;

  float* ws   = (float*)d_ws;
  float* xp_e = ws;                               // 64*1024*64
  float* xp_d = xp_e + (size_t)SLEN*G4*64;        // 32*1024*64
  float* h0P  = xp_d + (size_t)TLEN*G4*64;        // 256*64
  float* h1P  = h0P + HID*64;
  float* c0P  = h1P + HID*64;
  float* c1P  = c0P + HID*64;
  float* h0R  = c1P + HID*64;                     // 4*64*256
  float* p1R  = h0R + 4*64*HID;                   // 4*64*1024
  float* pval = p1R + 4*64*G4;                    // 64*1024
  int*   pidx = (int*)(pval + (size_t)B*1024);    // 64*1024
  int*   buf  = pidx + (size_t)B*1024;            // 64*32
  int*   fA   = buf + B*TLEN;                     // 64
  int*   fB1  = fA + 64;                          // 64
  int*   fB2  = fB1 + 64;                         // 64
  float* WT0  = (float*)(fB2 + 64);               // 256*1024 x3 (reused enc->dec)
  float* WT1i = WT0  + HID*G4;
  float* WT1h = WT1i + HID*G4;

  k_init<<<1, 64, 0, stream>>>(target_seq, buf);
  k_zero<<<1, 256, 0, stream>>>(fA);

  dim3 trg(16, 4);
  // encoder weights -> WT, then encoder
  k_tr<<<trg, 256, 0, stream>>>(enc_Whh,                   WT0);
  k_tr<<<trg, 256, 0, stream>>>(enc_Wih + (size_t)G4*EMBD, WT1i);
  k_tr<<<trg, 256, 0, stream>>>(enc_Whh + (size_t)G4*HID,  WT1h);
  k_xproj<<<dim3(32, SLEN), 256, 0, stream>>>(input_seq, SLEN, 0, enc_emb,
        enc_Wih, enc_b, xp_e);
  k_pipe<<<192, 1024, 0, stream>>>(xp_e, SLEN,
        WT0, WT1i, WT1h, enc_b + G4,
        h0P, h1P, c0P, c1P, h0R, p1R, fA, fB1, fB2, 0, 1);

  // decoder weights -> WT (stream-ordered overwrite is safe)
  k_tr<<<trg, 256, 0, stream>>>(dec_Whh,                   WT0);
  k_tr<<<trg, 256, 0, stream>>>(dec_Wih + (size_t)G4*EMBD, WT1i);
  k_tr<<<trg, 256, 0, stream>>>(dec_Whh + (size_t)G4*HID,  WT1h);

  // decoder greedy loop (outer step t replays positions 0..t)
  int fb = SLEN;
  for (int t = 0; t < NPRED; t++){
    k_xproj<<<dim3(32, 1), 256, 0, stream>>>(buf, TLEN, t, dec_emb,
        dec_Wih, dec_b, xp_d);
    k_pipe<<<192, 1024, 0, stream>>>(xp_d, t+1,
        WT0, WT1i, WT1h, dec_b + G4,
        h0P, h1P, c0P, c1P, h0R, p1R, fA, fB1, fB2, fb, 0);
    fb += t + 1;
    k_pred<<<1000, 256, 0, stream>>>(h1P, W_out, b_out, out, t, pval, pidx);
    k_amax<<<B, 256, 0, stream>>>(pval, pidx, buf, t);
  }
}